// Round 5
// baseline (329.421 us; speedup 1.0000x reference)
//
#include <hip/hip_runtime.h>
#include <hip/hip_bf16.h>

// Problem constants (S, B, E, H) = (2048, 2, 1024, 16), HD = 64
#define S_LEN 2048
#define BATCH 2
#define EMB   1024
#define NH    16
#define HDIM  64
#define MROWS (S_LEN * BATCH)   // 4096 rows of the (S,B,E) matrices

typedef _Float16 half4v __attribute__((ext_vector_type(4)));
typedef _Float16 half8v __attribute__((ext_vector_type(8)));
typedef float    f32x4  __attribute__((ext_vector_type(4)));

static __device__ __forceinline__ half8v join44(half4v lo, half4v hi) {
  half8v r;
  r[0] = lo[0]; r[1] = lo[1]; r[2] = lo[2]; r[3] = lo[3];
  r[4] = hi[0]; r[5] = hi[1]; r[6] = hi[2]; r[7] = hi[3];
  return r;
}

// async global->LDS, 16B per lane. dst = wave-uniform base (HW adds lane*16).
static __device__ __forceinline__ void gl_lds16(const _Float16* src, void* dst) {
  __builtin_amdgcn_global_load_lds(
      (const __attribute__((address_space(1))) void*)src,
      (__attribute__((address_space(3))) void*)dst, 16, 0, 0);
}

// ---------------------------------------------------------------------------
// Fused f32 -> f16 convert of all five arrays (q, k, v, ipw, opw).
// ---------------------------------------------------------------------------
__global__ __launch_bounds__(256) void cvt_all(
    const float* __restrict__ q, const float* __restrict__ k,
    const float* __restrict__ v, const float* __restrict__ ipw,
    const float* __restrict__ opw, _Float16* __restrict__ qo,
    _Float16* __restrict__ ko, _Float16* __restrict__ vo,
    _Float16* __restrict__ ipo, _Float16* __restrict__ opo) {
  const int i = blockIdx.x * 256 + threadIdx.x;
  const float* src;
  _Float16* dst;
  int off;
  if (i < 1048576) { src = q; dst = qo; off = i; }
  else if (i < 2097152) { src = k; dst = ko; off = i - 1048576; }
  else if (i < 3145728) { src = v; dst = vo; off = i - 2097152; }
  else if (i < 3932160) { src = ipw; dst = ipo; off = i - 3145728; }
  else { src = opw; dst = opo; off = i - 3932160; }
  const float4 f = ((const float4*)src)[off];
  half4v hv;
  hv[0] = (_Float16)f.x; hv[1] = (_Float16)f.y;
  hv[2] = (_Float16)f.z; hv[3] = (_Float16)f.w;
  ((half4v*)dst)[off] = hv;
}

// ---------------------------------------------------------------------------
// Stage one 128x64-half tile (16KB) via 4 gload_lds per wave, T2 XOR swizzle
// applied to the GLOBAL source granule (rule 21: linear LDS dest).
// ---------------------------------------------------------------------------
static __device__ __forceinline__ void stage_tile(const _Float16* gsrc,
                                                  _Float16* lds, int w,
                                                  int lane) {
#pragma unroll
  for (int i = 0; i < 4; i++) {
    const int base = (w << 12) + (i << 10);
    const int doff = base + (lane << 4);
    const int row = doff >> 7;
    const int colb = (doff & 127) ^ ((row & 7) << 4);
    gl_lds16(gsrc + (size_t)row * EMB + (colb >> 1), (char*)lds + base);
  }
}

// ---------------------------------------------------------------------------
// TN GEMM: C[M,N] = A[M,K] @ W[N,K]^T + bias[N]. All-f16 operands, K=1024,
// tile 128x128, BK=64, double-buffered (T3 minimal 2-phase), XCD-swizzled.
// MODE 1 (in-proj): z selects q/k/v; epilogue L2-normalizes (z<2) and folds
//   log2e/clip(tau,.01) into q (z==0); f16 (B,H,S,HD) out.
// MODE 0 (out-proj): f32 row-major out.
// ---------------------------------------------------------------------------
template <int MODE>
__global__ __launch_bounds__(256, 2) void gemm16(
    const _Float16* __restrict__ Abase, const _Float16* __restrict__ Wbase,
    const float* __restrict__ ball, const float* __restrict__ tau,
    void* __restrict__ dstv) {
  __shared__ __align__(16) _Float16 As[2][128 * 64];
  __shared__ __align__(16) _Float16 Bs[2][128 * 64];

  const int tid = threadIdx.x, lane = tid & 63, w = tid >> 6;
  const int g = lane >> 4, r16 = lane & 15;

  // XCD-aware bijective swizzle of the flat block id
  constexpr int NWG = MODE ? 768 : 256;
  constexpr int CHUNK = NWG / 8;
  int flat = blockIdx.x + 8 * (blockIdx.y + 32 * blockIdx.z);
  flat = (flat & 7) * CHUNK + (flat >> 3);
  const int bx = flat & 7;
  const int by = (flat >> 3) & 31;
  const int bz = MODE ? (flat >> 8) : 0;

  const int bm = by * 128, bn = bx * 128;
  const int wr = (w >> 1) * 64, wc = (w & 1) * 64;
  const int swz = (r16 & 7) << 4;

  const _Float16* A = Abase + (MODE ? (size_t)bz * MROWS * EMB : 0);
  const _Float16* W = Wbase + (MODE ? (size_t)bz * EMB * EMB : 0);
  const float* bias = ball + (MODE ? bz * EMB : 0);

  f32x4 acc[4][4];
#pragma unroll
  for (int m = 0; m < 4; m++)
#pragma unroll
    for (int n = 0; n < 4; n++) acc[m][n] = (f32x4){0.f, 0.f, 0.f, 0.f};

  const _Float16* Ap = A + (size_t)bm * EMB;
  const _Float16* Wp = W + (size_t)bn * EMB;

  // prologue: stage K-tile 0 into buffer 0
  stage_tile(Ap, As[0], w, lane);
  stage_tile(Wp, Bs[0], w, lane);
  __syncthreads();

  int cur = 0;
  for (int t = 0; t < 16; t++) {
    if (t < 15) {
      stage_tile(Ap + (t + 1) * 64, As[cur ^ 1], w, lane);
      stage_tile(Wp + (t + 1) * 64, Bs[cur ^ 1], w, lane);
    }
#pragma unroll
    for (int kk = 0; kk < 2; kk++) {
      half8v af[4], bf[4];
      const int cA = kk * 64 + (g << 3);
#pragma unroll
      for (int m = 0; m < 4; m++) {
        const char* rb = (const char*)(As[cur]) + ((wr + m * 16 + r16) << 7);
        af[m] = join44(*(const half4v*)(rb + (cA ^ swz)),
                       *(const half4v*)(rb + ((cA + 32) ^ swz)));
      }
#pragma unroll
      for (int n = 0; n < 4; n++) {
        const char* rb = (const char*)(Bs[cur]) + ((wc + n * 16 + r16) << 7);
        bf[n] = join44(*(const half4v*)(rb + (cA ^ swz)),
                       *(const half4v*)(rb + ((cA + 32) ^ swz)));
      }
#pragma unroll
      for (int m = 0; m < 4; m++)
#pragma unroll
        for (int n = 0; n < 4; n++)
          acc[m][n] = __builtin_amdgcn_mfma_f32_16x16x32_f16(af[m], bf[n],
                                                             acc[m][n], 0, 0, 0);
    }
    __syncthreads();  // drains vmcnt(0): next buffer ready
    cur ^= 1;
  }

  // epilogue. C/D frag: row = 4*(lane>>4)+reg, col = lane&15 (verified).
  float bcol[4];
#pragma unroll
  for (int n = 0; n < 4; n++) bcol[n] = bias[bn + wc + n * 16 + r16];

  if (MODE == 1) {
    // this wave's 4 n-frags cover one full 64-wide head row
    const int hw = (bn + wc) >> 6;
    // fold log2(e) (exp2-domain softmax) and 1/clip(tau) into q
    const float tsc =
        (bz == 0) ? 1.4426950408889634f / fmaxf(tau[hw], 0.01f) : 1.0f;
    _Float16* dst = (_Float16*)dstv + (size_t)bz * MROWS * EMB;
#pragma unroll
    for (int m = 0; m < 4; m++)
#pragma unroll
      for (int r = 0; r < 4; r++) {
        float v[4], ss = 0.f;
#pragma unroll
        for (int n = 0; n < 4; n++) {
          v[n] = acc[m][n][r] + bcol[n];
          ss += v[n] * v[n];
        }
        ss += __shfl_xor(ss, 1, 64);
        ss += __shfl_xor(ss, 2, 64);
        ss += __shfl_xor(ss, 4, 64);
        ss += __shfl_xor(ss, 8, 64);
        const float sc = (bz == 2) ? 1.0f : tsc / fmaxf(sqrtf(ss), 1e-12f);
        const int rr = bm + wr + m * 16 + g * 4 + r;
        const int s = rr >> 1, bb = rr & 1;
        const size_t rowb = (((size_t)(bb * NH + hw)) * S_LEN + s) * HDIM;
#pragma unroll
        for (int n = 0; n < 4; n++)
          dst[rowb + n * 16 + r16] = (_Float16)(v[n] * sc);
      }
  } else {
#pragma unroll
    for (int m = 0; m < 4; m++) {
      const int grow = bm + wr + m * 16 + g * 4;
#pragma unroll
      for (int n = 0; n < 4; n++) {
        const int gcol = bn + wc + n * 16 + r16;
#pragma unroll
        for (int r = 0; r < 4; r++)
          ((float*)dstv)[(size_t)(grow + r) * EMB + gcol] =
              acc[m][n][r] + bcol[n];
      }
    }
  }
}

// ---------------------------------------------------------------------------
// Flash attention, swapped-QK^T. K-frags read DIRECT from global (L1/L2-hot
// 8KB tile; no K LDS staging). V^T double-buffered in LDS (T14 split).
// exp2-domain softmax (log2e folded into q), T13 defer-rescale THR=8,
// lazy cross-lane l-reduction. 4 waves x 32 q-rows, KV tile = 64.
// ---------------------------------------------------------------------------
__global__ __launch_bounds__(256) void attn_fwd(const _Float16* __restrict__ qn,
                                                const _Float16* __restrict__ kn,
                                                const _Float16* __restrict__ vv,
                                                _Float16* __restrict__ outp) {
  __shared__ __align__(16) _Float16 Vt[2][64 * 64];  // [d][key], swizzled

  const int tid = threadIdx.x, lane = tid & 63, w = tid >> 6;
  const int g = lane >> 4, r16 = lane & 15;

  // XCD swizzle: nwg = 512, 16 q-tiles (x) fastest -> same head groups on XCD
  int flat = blockIdx.x + (blockIdx.y << 4);
  flat = (flat & 7) * 64 + (flat >> 3);
  const int bx = flat & 15, bh = flat >> 4;
  const int b = bh >> 4, h = bh & 15;
  const int q0 = bx * 128;

  const size_t hb = (size_t)bh * S_LEN * HDIM;
  const _Float16* Q = qn + hb;
  const _Float16* Kp = kn + hb;
  const _Float16* Vp = vv + hb;

  // Q as B-operand fragments: qf[qg][kk], lane holds Q[q=r16][d]
  half8v qf[2][2];
#pragma unroll
  for (int qg = 0; qg < 2; qg++) {
    const _Float16* qp = Q + (size_t)(q0 + w * 32 + qg * 16 + r16) * HDIM;
#pragma unroll
    for (int kk = 0; kk < 2; kk++)
      qf[qg][kk] = join44(*(const half4v*)(qp + kk * 32 + 4 * g),
                          *(const half4v*)(qp + kk * 32 + 16 + 4 * g));
  }

  f32x4 o[2][4];
#pragma unroll
  for (int qg = 0; qg < 2; qg++)
#pragma unroll
    for (int n = 0; n < 4; n++) o[qg][n] = (f32x4){0.f, 0.f, 0.f, 0.f};
  float mr[2] = {-1e30f, -1e30f};
  float lr[2] = {0.f, 0.f};  // per-lane PARTIAL sums (reduced at end)

  auto vload = [&](half8v& v0, half8v& v1, int t0) {
    const _Float16* vp0 = Vp + (size_t)(t0 + w * 8) * HDIM + lane;
    const _Float16* vp1 = Vp + (size_t)(t0 + (w + 4) * 8) * HDIM + lane;
#pragma unroll
    for (int j = 0; j < 8; j++) {
      v0[j] = vp0[j * HDIM];
      v1[j] = vp1[j * HDIM];
    }
  };
  auto vwrite = [&](int buf, half8v v0, half8v v1) {
    char* vb = (char*)(Vt[buf]) + (lane << 7);
    const int lw = (lane & 7) << 4;
    *(half8v*)(vb + ((w << 4) ^ lw)) = v0;
    *(half8v*)(vb + (((w + 4) << 4) ^ lw)) = v1;
  };

  // prologue: V tile 0 into buffer 0
  {
    half8v v0, v1;
    vload(v0, v1, 0);
    vwrite(0, v0, v1);
  }
  __syncthreads();

  int cur = 0;
  for (int t0 = 0; t0 < S_LEN; t0 += 64) {
    const int nxt = cur ^ 1;
    const bool more = (t0 + 64) < S_LEN;
    half8v vr0, vr1;
    if (more) vload(vr0, vr1, t0 + 64);  // issue early (T14)

    // ---- S^T = K @ Q^T, K-frags straight from global (L1/L2-resident)
    f32x4 sv[2][4];
#pragma unroll
    for (int qg = 0; qg < 2; qg++)
#pragma unroll
      for (int n = 0; n < 4; n++) sv[qg][n] = (f32x4){0.f, 0.f, 0.f, 0.f};
    __builtin_amdgcn_s_setprio(1);
#pragma unroll
    for (int n = 0; n < 4; n++) {
      const _Float16* kp = Kp + (size_t)(t0 + n * 16 + r16) * HDIM;
      const half8v kf0 = join44(*(const half4v*)(kp + 4 * g),
                                *(const half4v*)(kp + 16 + 4 * g));
      const half8v kf1 = join44(*(const half4v*)(kp + 32 + 4 * g),
                                *(const half4v*)(kp + 48 + 4 * g));
#pragma unroll
      for (int qg = 0; qg < 2; qg++) {
        sv[qg][n] = __builtin_amdgcn_mfma_f32_16x16x32_f16(kf0, qf[qg][0],
                                                           sv[qg][n], 0, 0, 0);
        sv[qg][n] = __builtin_amdgcn_mfma_f32_16x16x32_f16(kf1, qf[qg][1],
                                                           sv[qg][n], 0, 0, 0);
      }
    }
    __builtin_amdgcn_s_setprio(0);

    // ---- softmax (log2 domain), T13 defer-rescale, lazy l
    half8v pf[2][2];
#pragma unroll
    for (int qg = 0; qg < 2; qg++) {
      float pm = -1e30f;
#pragma unroll
      for (int n = 0; n < 4; n++)
#pragma unroll
        for (int r = 0; r < 4; r++) pm = fmaxf(pm, sv[qg][n][r]);
      pm = fmaxf(pm, __shfl_xor(pm, 16, 64));
      pm = fmaxf(pm, __shfl_xor(pm, 32, 64));
      float mn;
      if (__all(pm - mr[qg] <= 8.0f)) {
        mn = mr[qg];  // deferred: p <= 2^8, f16-safe
      } else {
        mn = fmaxf(mr[qg], pm);
        const float scq = __builtin_amdgcn_exp2f(mr[qg] - mn);
        mr[qg] = mn;
        lr[qg] *= scq;
        float srow[4];
#pragma unroll
        for (int r = 0; r < 4; r++) srow[r] = __shfl(scq, 4 * g + r, 64);
#pragma unroll
        for (int n = 0; n < 4; n++)
#pragma unroll
          for (int r = 0; r < 4; r++) o[qg][n][r] *= srow[r];
      }
      float ps = 0.f;
#pragma unroll
      for (int n = 0; n < 4; n++)
#pragma unroll
        for (int r = 0; r < 4; r++) {
          const float p = __builtin_amdgcn_exp2f(sv[qg][n][r] - mn);
          sv[qg][n][r] = p;
          ps += p;
        }
      lr[qg] += ps;  // per-lane partial; cross-lane reduce at end
#pragma unroll
      for (int kk = 0; kk < 2; kk++) {
        half8v t;
#pragma unroll
        for (int j = 0; j < 8; j++)
          t[j] = (_Float16)sv[qg][2 * kk + (j >> 2)][j & 3];
        pf[qg][kk] = t;
      }
    }

    // ---- O += P @ V from Vt[cur]
    __builtin_amdgcn_s_setprio(1);
#pragma unroll
    for (int n = 0; n < 4; n++) {
      const char* vb = (const char*)(Vt[cur]) + ((n * 16 + r16) << 7);
      const int s7 = (r16 & 7) << 4;
      const half8v vf0 = join44(*(const half4v*)(vb + ((8 * g) ^ s7)),
                                *(const half4v*)(vb + ((8 * g + 32) ^ s7)));
      const half8v vf1 = join44(*(const half4v*)(vb + ((8 * g + 64) ^ s7)),
                                *(const half4v*)(vb + ((8 * g + 96) ^ s7)));
#pragma unroll
      for (int qg = 0; qg < 2; qg++) {
        o[qg][n] = __builtin_amdgcn_mfma_f32_16x16x32_f16(pf[qg][0], vf0,
                                                          o[qg][n], 0, 0, 0);
        o[qg][n] = __builtin_amdgcn_mfma_f32_16x16x32_f16(pf[qg][1], vf1,
                                                          o[qg][n], 0, 0, 0);
      }
    }
    __builtin_amdgcn_s_setprio(0);

    if (more) vwrite(nxt, vr0, vr1);  // write-late (T14)
    __syncthreads();
    cur = nxt;
  }

  // epilogue: finish l reduction, out rows q = 4g+r, cols d = 16n+r16
#pragma unroll
  for (int qg = 0; qg < 2; qg++) {
    float lf = lr[qg];
    lf += __shfl_xor(lf, 16, 64);
    lf += __shfl_xor(lf, 32, 64);
    const float li = 1.0f / lf;
    float lrow[4];
#pragma unroll
    for (int r = 0; r < 4; r++) lrow[r] = __shfl(li, 4 * g + r, 64);
#pragma unroll
    for (int n = 0; n < 4; n++) {
      const int e = h * HDIM + n * 16 + r16;
#pragma unroll
      for (int r = 0; r < 4; r++) {
        const int srow = q0 + w * 32 + qg * 16 + 4 * g + r;
        outp[((size_t)srow * BATCH + b) * EMB + e] =
            (_Float16)(o[qg][n][r] * lrow[r]);
      }
    }
  }
}

// ---------------------------------------------------------------------------
extern "C" void kernel_launch(void* const* d_in, const int* in_sizes, int n_in,
                              void* d_out, int out_size, void* d_ws,
                              size_t ws_size, hipStream_t stream) {
  const float* query = (const float*)d_in[0];
  const float* key   = (const float*)d_in[1];
  const float* value = (const float*)d_in[2];
  const float* ipw   = (const float*)d_in[3];  // (3E, E)
  const float* ipb   = (const float*)d_in[4];  // (3E,)
  const float* opw   = (const float*)d_in[5];  // (E, E)
  const float* opb   = (const float*)d_in[6];  // (E,)
  const float* tau   = (const float*)d_in[7];  // (1,H,1,1)

  // workspace (f16): qin|kin|vin, ipw16, opw16, qbuf|kbuf|vbuf; abuf = qin
  _Float16* qin   = (_Float16*)d_ws;
  _Float16* kin   = qin + (size_t)MROWS * EMB;
  _Float16* vin   = kin + (size_t)MROWS * EMB;
  _Float16* ipw16 = vin + (size_t)MROWS * EMB;
  _Float16* opw16 = ipw16 + (size_t)3 * EMB * EMB;
  _Float16* qbuf  = opw16 + (size_t)EMB * EMB;
  _Float16* kbuf  = qbuf + (size_t)MROWS * EMB;
  _Float16* vbuf  = kbuf + (size_t)MROWS * EMB;
  _Float16* abuf  = qin;  // qin dead after in-proj

  cvt_all<<<16384, 256, 0, stream>>>(query, key, value, ipw, opw, qin, kin,
                                     vin, ipw16, opw16);

  // fused q/k/v in-projection + per-head L2 norm + tau/log2e fold
  gemm16<1><<<dim3(8, 32, 3), 256, 0, stream>>>(qin, ipw16, ipb, tau, qbuf);

  attn_fwd<<<dim3(16, 32), 256, 0, stream>>>(qbuf, kbuf, vbuf, abuf);

  gemm16<0><<<dim3(8, 32, 1), 256, 0, stream>>>(abuf, opw16, opb, nullptr,
                                                d_out);
}

// Round 6
// 268.480 us; speedup vs baseline: 1.2270x; 1.2270x over previous
//
#include <hip/hip_runtime.h>
#include <hip/hip_bf16.h>

// Problem constants (S, B, E, H) = (2048, 2, 1024, 16), HD = 64
#define S_LEN 2048
#define BATCH 2
#define EMB   1024
#define NH    16
#define HDIM  64
#define MROWS (S_LEN * BATCH)   // 4096 rows of the (S,B,E) matrices

typedef _Float16 half2v __attribute__((ext_vector_type(2)));
typedef _Float16 half4v __attribute__((ext_vector_type(4)));
typedef _Float16 half8v __attribute__((ext_vector_type(8)));
typedef float    f32x4  __attribute__((ext_vector_type(4)));

static __device__ __forceinline__ half8v join44(half4v lo, half4v hi) {
  half8v r;
  r[0] = lo[0]; r[1] = lo[1]; r[2] = lo[2]; r[3] = lo[3];
  r[4] = hi[0]; r[5] = hi[1]; r[6] = hi[2]; r[7] = hi[3];
  return r;
}

// packed f32x2 -> f16x2 (v_cvt_pkrtz_f16_f32)
static __device__ __forceinline__ half2v pk2(float a, float b) {
  auto t = __builtin_amdgcn_cvt_pkrtz(a, b);
  half2v r;
  __builtin_memcpy(&r, &t, sizeof(r));
  return r;
}

// async global->LDS, 16B per lane. dst = wave-uniform base (HW adds lane*16).
static __device__ __forceinline__ void gl_lds16(const _Float16* src, void* dst) {
  __builtin_amdgcn_global_load_lds(
      (const __attribute__((address_space(1))) void*)src,
      (__attribute__((address_space(3))) void*)dst, 16, 0, 0);
}

// ---------------------------------------------------------------------------
// Fused f32 -> f16 convert of all five arrays (q, k, v, ipw, opw).
// ---------------------------------------------------------------------------
__global__ __launch_bounds__(256) void cvt_all(
    const float* __restrict__ q, const float* __restrict__ k,
    const float* __restrict__ v, const float* __restrict__ ipw,
    const float* __restrict__ opw, _Float16* __restrict__ qo,
    _Float16* __restrict__ ko, _Float16* __restrict__ vo,
    _Float16* __restrict__ ipo, _Float16* __restrict__ opo) {
  const int i = blockIdx.x * 256 + threadIdx.x;
  const float* src;
  _Float16* dst;
  int off;
  if (i < 1048576) { src = q; dst = qo; off = i; }
  else if (i < 2097152) { src = k; dst = ko; off = i - 1048576; }
  else if (i < 3145728) { src = v; dst = vo; off = i - 2097152; }
  else if (i < 3932160) { src = ipw; dst = ipo; off = i - 3145728; }
  else { src = opw; dst = opo; off = i - 3932160; }
  const float4 f = ((const float4*)src)[off];
  half4v hv;
  hv[0] = (_Float16)f.x; hv[1] = (_Float16)f.y;
  hv[2] = (_Float16)f.z; hv[3] = (_Float16)f.w;
  ((half4v*)dst)[off] = hv;
}

// ---------------------------------------------------------------------------
// Stage one 128x64-half tile (16KB) via 4 gload_lds per wave, T2 XOR swizzle
// applied to the GLOBAL source granule (rule 21: linear LDS dest).
// ---------------------------------------------------------------------------
static __device__ __forceinline__ void stage_tile(const _Float16* gsrc,
                                                  _Float16* lds, int w,
                                                  int lane) {
#pragma unroll
  for (int i = 0; i < 4; i++) {
    const int base = (w << 12) + (i << 10);
    const int doff = base + (lane << 4);
    const int row = doff >> 7;
    const int colb = (doff & 127) ^ ((row & 7) << 4);
    gl_lds16(gsrc + (size_t)row * EMB + (colb >> 1), (char*)lds + base);
  }
}

// ---------------------------------------------------------------------------
// TN GEMM: C[M,N] = A[M,K] @ W[N,K]^T + bias[N]. All-f16 operands, K=1024,
// tile 128x128, BK=64, double-buffered (T3 minimal 2-phase), XCD-swizzled.
// MODE 1 (in-proj): z selects q/k/v.
//   z=0: L2-normalize + fold log2e/clip(tau,.01); (B,H,S,HD) f16 out.
//   z=1: L2-normalize; (B,H,S,HD) f16 out.
//   z=2: raw; write V TRANSPOSED per head: [bh][d][s] f16 (for attn staging).
// MODE 0 (out-proj): f32 row-major out.
// ---------------------------------------------------------------------------
template <int MODE>
__global__ __launch_bounds__(256, 2) void gemm16(
    const _Float16* __restrict__ Abase, const _Float16* __restrict__ Wbase,
    const float* __restrict__ ball, const float* __restrict__ tau,
    void* __restrict__ dstv, _Float16* __restrict__ vtdst) {
  __shared__ __align__(16) _Float16 As[2][128 * 64];
  __shared__ __align__(16) _Float16 Bs[2][128 * 64];

  const int tid = threadIdx.x, lane = tid & 63, w = tid >> 6;
  const int g = lane >> 4, r16 = lane & 15;

  // XCD-aware bijective swizzle of the flat block id
  constexpr int NWG = MODE ? 768 : 256;
  constexpr int CHUNK = NWG / 8;
  int flat = blockIdx.x + 8 * (blockIdx.y + 32 * blockIdx.z);
  flat = (flat & 7) * CHUNK + (flat >> 3);
  const int bx = flat & 7;
  const int by = (flat >> 3) & 31;
  const int bz = MODE ? (flat >> 8) : 0;

  const int bm = by * 128, bn = bx * 128;
  const int wr = (w >> 1) * 64, wc = (w & 1) * 64;
  const int swz = (r16 & 7) << 4;

  const _Float16* A = Abase + (MODE ? (size_t)bz * MROWS * EMB : 0);
  const _Float16* W = Wbase + (MODE ? (size_t)bz * EMB * EMB : 0);
  const float* bias = ball + (MODE ? bz * EMB : 0);

  f32x4 acc[4][4];
#pragma unroll
  for (int m = 0; m < 4; m++)
#pragma unroll
    for (int n = 0; n < 4; n++) acc[m][n] = (f32x4){0.f, 0.f, 0.f, 0.f};

  const _Float16* Ap = A + (size_t)bm * EMB;
  const _Float16* Wp = W + (size_t)bn * EMB;

  // prologue: stage K-tile 0 into buffer 0
  stage_tile(Ap, As[0], w, lane);
  stage_tile(Wp, Bs[0], w, lane);
  __syncthreads();

  int cur = 0;
  for (int t = 0; t < 16; t++) {
    if (t < 15) {
      stage_tile(Ap + (t + 1) * 64, As[cur ^ 1], w, lane);
      stage_tile(Wp + (t + 1) * 64, Bs[cur ^ 1], w, lane);
    }
#pragma unroll
    for (int kk = 0; kk < 2; kk++) {
      half8v af[4], bf[4];
      const int cA = kk * 64 + (g << 3);
#pragma unroll
      for (int m = 0; m < 4; m++) {
        const char* rb = (const char*)(As[cur]) + ((wr + m * 16 + r16) << 7);
        af[m] = join44(*(const half4v*)(rb + (cA ^ swz)),
                       *(const half4v*)(rb + ((cA + 32) ^ swz)));
      }
#pragma unroll
      for (int n = 0; n < 4; n++) {
        const char* rb = (const char*)(Bs[cur]) + ((wc + n * 16 + r16) << 7);
        bf[n] = join44(*(const half4v*)(rb + (cA ^ swz)),
                       *(const half4v*)(rb + ((cA + 32) ^ swz)));
      }
#pragma unroll
      for (int m = 0; m < 4; m++)
#pragma unroll
        for (int n = 0; n < 4; n++)
          acc[m][n] = __builtin_amdgcn_mfma_f32_16x16x32_f16(af[m], bf[n],
                                                             acc[m][n], 0, 0, 0);
    }
    __syncthreads();  // drains vmcnt(0): next buffer ready
    cur ^= 1;
  }

  // epilogue. C/D frag: row = 4*(lane>>4)+reg, col = lane&15 (verified).
  float bcol[4];
#pragma unroll
  for (int n = 0; n < 4; n++) bcol[n] = bias[bn + wc + n * 16 + r16];

  if (MODE == 1) {
    // this wave's 4 n-frags cover one full 64-wide head row
    const int hw = (bn + wc) >> 6;
    // fold log2(e) (exp2-domain softmax) and 1/clip(tau) into q
    const float tsc =
        (bz == 0) ? 1.4426950408889634f / fmaxf(tau[hw], 0.01f) : 1.0f;
    if (bz == 2) {
      // V: write transposed per head: vtdst[bh][d][s]
#pragma unroll
      for (int m = 0; m < 4; m++)
#pragma unroll
        for (int r = 0; r < 4; r++) {
          const int rr = bm + wr + m * 16 + g * 4 + r;
          const int s = rr >> 1, bb = rr & 1;
#pragma unroll
          for (int n = 0; n < 4; n++) {
            const float v = acc[m][n][r] + bcol[n];
            vtdst[((size_t)(bb * NH + hw) * HDIM + n * 16 + r16) * S_LEN + s] =
                (_Float16)v;
          }
        }
    } else {
      _Float16* dst = (_Float16*)dstv + (size_t)bz * MROWS * EMB;
#pragma unroll
      for (int m = 0; m < 4; m++)
#pragma unroll
        for (int r = 0; r < 4; r++) {
          float v[4], ss = 0.f;
#pragma unroll
          for (int n = 0; n < 4; n++) {
            v[n] = acc[m][n][r] + bcol[n];
            ss += v[n] * v[n];
          }
          ss += __shfl_xor(ss, 1, 64);
          ss += __shfl_xor(ss, 2, 64);
          ss += __shfl_xor(ss, 4, 64);
          ss += __shfl_xor(ss, 8, 64);
          const float sc = tsc / fmaxf(sqrtf(ss), 1e-12f);
          const int rr = bm + wr + m * 16 + g * 4 + r;
          const int s = rr >> 1, bb = rr & 1;
          const size_t rowb = (((size_t)(bb * NH + hw)) * S_LEN + s) * HDIM;
#pragma unroll
          for (int n = 0; n < 4; n++)
            dst[rowb + n * 16 + r16] = (_Float16)(v[n] * sc);
        }
    }
  } else {
#pragma unroll
    for (int m = 0; m < 4; m++) {
      const int grow = bm + wr + m * 16 + g * 4;
#pragma unroll
      for (int n = 0; n < 4; n++) {
        const int gcol = bn + wc + n * 16 + r16;
#pragma unroll
        for (int r = 0; r < 4; r++)
          ((float*)dstv)[(size_t)(grow + r) * EMB + gcol] =
              acc[m][n][r] + bcol[n];
      }
    }
  }
}

// ---------------------------------------------------------------------------
// Flash attention, swapped-QK^T. K [key][d] and V^T [d][key] tiles both
// staged via global_load_lds (V pre-transposed by in-proj), double-buffered,
// one barrier per tile. exp2-domain softmax (log2e folded into q), T13
// defer-rescale THR=8, lazy cross-lane l, packed P-convert (cvt_pkrtz).
// 4 waves x 32 q-rows, KV tile = 64.
// ---------------------------------------------------------------------------
__global__ __launch_bounds__(256) void attn_fwd(const _Float16* __restrict__ qn,
                                                const _Float16* __restrict__ kn,
                                                const _Float16* __restrict__ vt,
                                                _Float16* __restrict__ outp) {
  __shared__ __align__(16) _Float16 Kt[2][64 * 64];  // [key][d], swizzled
  __shared__ __align__(16) _Float16 Vt[2][64 * 64];  // [d][key], swizzled

  const int tid = threadIdx.x, lane = tid & 63, w = tid >> 6;
  const int g = lane >> 4, r16 = lane & 15;
  const int s7 = (r16 & 7) << 4;

  // XCD swizzle: nwg = 512, 16 q-tiles (x) fastest
  int flat = blockIdx.x + (blockIdx.y << 4);
  flat = (flat & 7) * 64 + (flat >> 3);
  const int bx = flat & 15, bh = flat >> 4;
  const int b = bh >> 4, h = bh & 15;
  const int q0 = bx * 128;

  const _Float16* Q = qn + (size_t)bh * S_LEN * HDIM;
  const _Float16* Kp = kn + (size_t)bh * S_LEN * HDIM;
  const _Float16* VTp = vt + (size_t)bh * HDIM * S_LEN;

  // Q as B-operand fragments: qf[qg][kk], lane holds Q[q=r16][d]
  half8v qf[2][2];
#pragma unroll
  for (int qg = 0; qg < 2; qg++) {
    const _Float16* qp = Q + (size_t)(q0 + w * 32 + qg * 16 + r16) * HDIM;
#pragma unroll
    for (int kk = 0; kk < 2; kk++)
      qf[qg][kk] = join44(*(const half4v*)(qp + kk * 32 + 4 * g),
                          *(const half4v*)(qp + kk * 32 + 16 + 4 * g));
  }

  f32x4 o[2][4];
#pragma unroll
  for (int qg = 0; qg < 2; qg++)
#pragma unroll
    for (int n = 0; n < 4; n++) o[qg][n] = (f32x4){0.f, 0.f, 0.f, 0.f};
  float mr[2] = {-1e30f, -1e30f};
  float lr[2] = {0.f, 0.f};  // per-lane PARTIAL sums (reduced at end)

  // stage K tile (rows=key, stride HDIM) and V^T tile (rows=d, stride S_LEN)
  auto stage2 = [&](_Float16* ldsK, _Float16* ldsV, int t0) {
#pragma unroll
    for (int i = 0; i < 2; i++) {
      const int base = (w << 11) + (i << 10);
      const int doff = base + (lane << 4);
      const int row = doff >> 7;
      const int colh = ((doff & 127) ^ ((row & 7) << 4)) >> 1;
      gl_lds16(Kp + (size_t)(t0 + row) * HDIM + colh, (char*)ldsK + base);
      gl_lds16(VTp + (size_t)row * S_LEN + t0 + colh, (char*)ldsV + base);
    }
  };

  // prologue: tile 0 into buffer 0
  stage2(Kt[0], Vt[0], 0);
  __syncthreads();

  int cur = 0;
  for (int t0 = 0; t0 < S_LEN; t0 += 64) {
    const int nxt = cur ^ 1;
    if (t0 + 64 < S_LEN) stage2(Kt[nxt], Vt[nxt], t0 + 64);  // prefetch

    // ---- S^T = K @ Q^T from Kt[cur]
    f32x4 sv[2][4];
#pragma unroll
    for (int qg = 0; qg < 2; qg++)
#pragma unroll
      for (int n = 0; n < 4; n++) sv[qg][n] = (f32x4){0.f, 0.f, 0.f, 0.f};
    __builtin_amdgcn_s_setprio(1);
#pragma unroll
    for (int n = 0; n < 4; n++) {
      const char* kb = (const char*)(Kt[cur]) + ((n * 16 + r16) << 7);
      const half8v kf0 = join44(*(const half4v*)(kb + ((8 * g) ^ s7)),
                                *(const half4v*)(kb + ((8 * g + 32) ^ s7)));
      const half8v kf1 = join44(*(const half4v*)(kb + ((8 * g + 64) ^ s7)),
                                *(const half4v*)(kb + ((8 * g + 96) ^ s7)));
#pragma unroll
      for (int qg = 0; qg < 2; qg++) {
        sv[qg][n] = __builtin_amdgcn_mfma_f32_16x16x32_f16(kf0, qf[qg][0],
                                                           sv[qg][n], 0, 0, 0);
        sv[qg][n] = __builtin_amdgcn_mfma_f32_16x16x32_f16(kf1, qf[qg][1],
                                                           sv[qg][n], 0, 0, 0);
      }
    }
    __builtin_amdgcn_s_setprio(0);

    // ---- softmax (log2 domain), T13 defer-rescale, lazy l, packed cvt
    half8v pf[2][2];
#pragma unroll
    for (int qg = 0; qg < 2; qg++) {
      float pm = -1e30f;
#pragma unroll
      for (int n = 0; n < 4; n++)
#pragma unroll
        for (int r = 0; r < 4; r++) pm = fmaxf(pm, sv[qg][n][r]);
      pm = fmaxf(pm, __shfl_xor(pm, 16, 64));
      pm = fmaxf(pm, __shfl_xor(pm, 32, 64));
      float mn;
      if (__all(pm - mr[qg] <= 8.0f)) {
        mn = mr[qg];  // deferred: p <= 2^8, f16-safe
      } else {
        mn = fmaxf(mr[qg], pm);
        const float scq = __builtin_amdgcn_exp2f(mr[qg] - mn);
        mr[qg] = mn;
        lr[qg] *= scq;
        float srow[4];
#pragma unroll
        for (int r = 0; r < 4; r++) srow[r] = __shfl(scq, 4 * g + r, 64);
#pragma unroll
        for (int n = 0; n < 4; n++)
#pragma unroll
          for (int r = 0; r < 4; r++) o[qg][n][r] *= srow[r];
      }
      float ps = 0.f;
#pragma unroll
      for (int n = 0; n < 4; n++)
#pragma unroll
        for (int r = 0; r < 4; r++) {
          const float p = __builtin_amdgcn_exp2f(sv[qg][n][r] - mn);
          sv[qg][n][r] = p;
          ps += p;
        }
      lr[qg] += ps;  // per-lane partial; cross-lane reduce at end
#pragma unroll
      for (int kk = 0; kk < 2; kk++) {
        union { half8v v8; half2v v2[4]; } u;
        u.v2[0] = pk2(sv[qg][2 * kk][0], sv[qg][2 * kk][1]);
        u.v2[1] = pk2(sv[qg][2 * kk][2], sv[qg][2 * kk][3]);
        u.v2[2] = pk2(sv[qg][2 * kk + 1][0], sv[qg][2 * kk + 1][1]);
        u.v2[3] = pk2(sv[qg][2 * kk + 1][2], sv[qg][2 * kk + 1][3]);
        pf[qg][kk] = u.v8;
      }
    }

    // ---- O += P @ V from Vt[cur]
    __builtin_amdgcn_s_setprio(1);
#pragma unroll
    for (int n = 0; n < 4; n++) {
      const char* vb = (const char*)(Vt[cur]) + ((n * 16 + r16) << 7);
      const half8v vf0 = join44(*(const half4v*)(vb + ((8 * g) ^ s7)),
                                *(const half4v*)(vb + ((8 * g + 32) ^ s7)));
      const half8v vf1 = join44(*(const half4v*)(vb + ((8 * g + 64) ^ s7)),
                                *(const half4v*)(vb + ((8 * g + 96) ^ s7)));
#pragma unroll
      for (int qg = 0; qg < 2; qg++) {
        o[qg][n] = __builtin_amdgcn_mfma_f32_16x16x32_f16(pf[qg][0], vf0,
                                                          o[qg][n], 0, 0, 0);
        o[qg][n] = __builtin_amdgcn_mfma_f32_16x16x32_f16(pf[qg][1], vf1,
                                                          o[qg][n], 0, 0, 0);
      }
    }
    __builtin_amdgcn_s_setprio(0);

    __syncthreads();  // drains vmcnt(0): next buffers ready
    cur = nxt;
  }

  // epilogue: finish l reduction, out rows q = 4g+r, cols d = 16n+r16
#pragma unroll
  for (int qg = 0; qg < 2; qg++) {
    float lf = lr[qg];
    lf += __shfl_xor(lf, 16, 64);
    lf += __shfl_xor(lf, 32, 64);
    const float li = 1.0f / lf;
    float lrow[4];
#pragma unroll
    for (int r = 0; r < 4; r++) lrow[r] = __shfl(li, 4 * g + r, 64);
#pragma unroll
    for (int n = 0; n < 4; n++) {
      const int e = h * HDIM + n * 16 + r16;
#pragma unroll
      for (int r = 0; r < 4; r++) {
        const int srow = q0 + w * 32 + qg * 16 + 4 * g + r;
        outp[((size_t)srow * BATCH + b) * EMB + e] =
            (_Float16)(o[qg][n][r] * lrow[r]);
      }
    }
  }
}

// ---------------------------------------------------------------------------
extern "C" void kernel_launch(void* const* d_in, const int* in_sizes, int n_in,
                              void* d_out, int out_size, void* d_ws,
                              size_t ws_size, hipStream_t stream) {
  const float* query = (const float*)d_in[0];
  const float* key   = (const float*)d_in[1];
  const float* value = (const float*)d_in[2];
  const float* ipw   = (const float*)d_in[3];  // (3E, E)
  const float* ipb   = (const float*)d_in[4];  // (3E,)
  const float* opw   = (const float*)d_in[5];  // (E, E)
  const float* opb   = (const float*)d_in[6];  // (E,)
  const float* tau   = (const float*)d_in[7];  // (1,H,1,1)

  // workspace (f16): qin|kin|vin, ipw16, opw16, qbuf|kbuf, vbufT; abuf = qin
  _Float16* qin   = (_Float16*)d_ws;
  _Float16* kin   = qin + (size_t)MROWS * EMB;
  _Float16* vin   = kin + (size_t)MROWS * EMB;
  _Float16* ipw16 = vin + (size_t)MROWS * EMB;
  _Float16* opw16 = ipw16 + (size_t)3 * EMB * EMB;
  _Float16* qbuf  = opw16 + (size_t)EMB * EMB;
  _Float16* kbuf  = qbuf + (size_t)MROWS * EMB;
  _Float16* vbufT = kbuf + (size_t)MROWS * EMB;   // (B,H,HD,S)
  _Float16* abuf  = qin;  // qin dead after in-proj

  cvt_all<<<16384, 256, 0, stream>>>(query, key, value, ipw, opw, qin, kin,
                                     vin, ipw16, opw16);

  // fused q/k/v in-projection + per-head L2 norm + tau/log2e fold + V^T
  gemm16<1><<<dim3(8, 32, 3), 256, 0, stream>>>(qin, ipw16, ipb, tau, qbuf,
                                                vbufT);

  attn_fwd<<<dim3(16, 32), 256, 0, stream>>>(qbuf, kbuf, vbufT, abuf);

  gemm16<0><<<dim3(8, 32, 1), 256, 0, stream>>>(abuf, opw16, opb, nullptr,
                                                d_out, nullptr);
}

// Round 7
// 260.927 us; speedup vs baseline: 1.2625x; 1.0289x over previous
//
#include <hip/hip_runtime.h>
#include <hip/hip_bf16.h>

// Problem constants (S, B, E, H) = (2048, 2, 1024, 16), HD = 64
#define S_LEN 2048
#define BATCH 2
#define EMB   1024
#define NH    16
#define HDIM  64
#define MROWS (S_LEN * BATCH)   // 4096 rows of the (S,B,E) matrices

typedef _Float16 half2v __attribute__((ext_vector_type(2)));
typedef _Float16 half4v __attribute__((ext_vector_type(4)));
typedef _Float16 half8v __attribute__((ext_vector_type(8)));
typedef float    f32x4  __attribute__((ext_vector_type(4)));

static __device__ __forceinline__ half8v join44(half4v lo, half4v hi) {
  half8v r;
  r[0] = lo[0]; r[1] = lo[1]; r[2] = lo[2]; r[3] = lo[3];
  r[4] = hi[0]; r[5] = hi[1]; r[6] = hi[2]; r[7] = hi[3];
  return r;
}

// packed f32x2 -> f16x2 (v_cvt_pkrtz_f16_f32)
static __device__ __forceinline__ half2v pk2(float a, float b) {
  auto t = __builtin_amdgcn_cvt_pkrtz(a, b);
  half2v r;
  __builtin_memcpy(&r, &t, sizeof(r));
  return r;
}

// async global->LDS, 16B per lane. dst = wave-uniform base (HW adds lane*16).
static __device__ __forceinline__ void gl_lds16(const _Float16* src, void* dst) {
  __builtin_amdgcn_global_load_lds(
      (const __attribute__((address_space(1))) void*)src,
      (__attribute__((address_space(3))) void*)dst, 16, 0, 0);
}

// ---------------------------------------------------------------------------
// Fused f32 -> f16 convert of all five arrays (q, k, v, ipw, opw).
// ---------------------------------------------------------------------------
__global__ __launch_bounds__(256) void cvt_all(
    const float* __restrict__ q, const float* __restrict__ k,
    const float* __restrict__ v, const float* __restrict__ ipw,
    const float* __restrict__ opw, _Float16* __restrict__ qo,
    _Float16* __restrict__ ko, _Float16* __restrict__ vo,
    _Float16* __restrict__ ipo, _Float16* __restrict__ opo) {
  const int i = blockIdx.x * 256 + threadIdx.x;
  const float* src;
  _Float16* dst;
  int off;
  if (i < 1048576) { src = q; dst = qo; off = i; }
  else if (i < 2097152) { src = k; dst = ko; off = i - 1048576; }
  else if (i < 3145728) { src = v; dst = vo; off = i - 2097152; }
  else if (i < 3932160) { src = ipw; dst = ipo; off = i - 3145728; }
  else { src = opw; dst = opo; off = i - 3932160; }
  const float4 f = ((const float4*)src)[off];
  half4v hv;
  hv[0] = (_Float16)f.x; hv[1] = (_Float16)f.y;
  hv[2] = (_Float16)f.z; hv[3] = (_Float16)f.w;
  ((half4v*)dst)[off] = hv;
}

// ---------------------------------------------------------------------------
// Stage one 128x64-half tile (16KB) via 4 gload_lds per wave, T2 XOR swizzle
// applied to the GLOBAL source granule (rule 21: linear LDS dest).
// ---------------------------------------------------------------------------
static __device__ __forceinline__ void stage_tile(const _Float16* gsrc,
                                                  _Float16* lds, int w,
                                                  int lane) {
#pragma unroll
  for (int i = 0; i < 4; i++) {
    const int base = (w << 12) + (i << 10);
    const int doff = base + (lane << 4);
    const int row = doff >> 7;
    const int colb = (doff & 127) ^ ((row & 7) << 4);
    gl_lds16(gsrc + (size_t)row * EMB + (colb >> 1), (char*)lds + base);
  }
}

// ---------------------------------------------------------------------------
// TN GEMM: C[M,N] = A[M,K] @ W[N,K]^T + bias[N]. All-f16 operands, K=1024,
// tile 128x128, BK=64, double-buffered, XCD-swizzled.
// MODE 1 (in-proj): z selects q/k/v.
//   z=0: L2-normalize + fold log2e/clip(tau,.01); (B,H,S,HD) f16, d PERMUTED.
//   z=1: L2-normalize; (B,H,S,HD) f16, d PERMUTED.
//   z=2: raw; V TRANSPOSED per head [bh][d][s], s PERMUTED within 64-tiles.
//   perm(k) = bit-swap so attn frag reads are single b128:
//   pos = ((k&12)<<2) | ((k&32)>>2) | ((k&16)>>2) | (k&3)
// MODE 0 (out-proj): f32 row-major out.
// ---------------------------------------------------------------------------
template <int MODE>
__global__ __launch_bounds__(256, 2) void gemm16(
    const _Float16* __restrict__ Abase, const _Float16* __restrict__ Wbase,
    const float* __restrict__ ball, const float* __restrict__ tau,
    void* __restrict__ dstv, _Float16* __restrict__ vtdst) {
  __shared__ __align__(16) _Float16 As[2][128 * 64];
  __shared__ __align__(16) _Float16 Bs[2][128 * 64];

  const int tid = threadIdx.x, lane = tid & 63, w = tid >> 6;
  const int g = lane >> 4, r16 = lane & 15;

  // XCD-aware bijective swizzle of the flat block id
  constexpr int NWG = MODE ? 768 : 256;
  constexpr int CHUNK = NWG / 8;
  int flat = blockIdx.x + 8 * (blockIdx.y + 32 * blockIdx.z);
  flat = (flat & 7) * CHUNK + (flat >> 3);
  const int bx = flat & 7;
  const int by = (flat >> 3) & 31;
  const int bz = MODE ? (flat >> 8) : 0;

  const int bm = by * 128, bn = bx * 128;
  const int wr = (w >> 1) * 64, wc = (w & 1) * 64;
  const int swz = (r16 & 7) << 4;

  const _Float16* A = Abase + (MODE ? (size_t)bz * MROWS * EMB : 0);
  const _Float16* W = Wbase + (MODE ? (size_t)bz * EMB * EMB : 0);
  const float* bias = ball + (MODE ? bz * EMB : 0);

  f32x4 acc[4][4];
#pragma unroll
  for (int m = 0; m < 4; m++)
#pragma unroll
    for (int n = 0; n < 4; n++) acc[m][n] = (f32x4){0.f, 0.f, 0.f, 0.f};

  const _Float16* Ap = A + (size_t)bm * EMB;
  const _Float16* Wp = W + (size_t)bn * EMB;

  stage_tile(Ap, As[0], w, lane);
  stage_tile(Wp, Bs[0], w, lane);
  __syncthreads();

  int cur = 0;
  for (int t = 0; t < 16; t++) {
    if (t < 15) {
      stage_tile(Ap + (t + 1) * 64, As[cur ^ 1], w, lane);
      stage_tile(Wp + (t + 1) * 64, Bs[cur ^ 1], w, lane);
    }
#pragma unroll
    for (int kk = 0; kk < 2; kk++) {
      half8v af[4], bf[4];
      const int cA = kk * 64 + (g << 3);
#pragma unroll
      for (int m = 0; m < 4; m++) {
        const char* rb = (const char*)(As[cur]) + ((wr + m * 16 + r16) << 7);
        af[m] = join44(*(const half4v*)(rb + (cA ^ swz)),
                       *(const half4v*)(rb + ((cA + 32) ^ swz)));
      }
#pragma unroll
      for (int n = 0; n < 4; n++) {
        const char* rb = (const char*)(Bs[cur]) + ((wc + n * 16 + r16) << 7);
        bf[n] = join44(*(const half4v*)(rb + (cA ^ swz)),
                       *(const half4v*)(rb + ((cA + 32) ^ swz)));
      }
#pragma unroll
      for (int m = 0; m < 4; m++)
#pragma unroll
        for (int n = 0; n < 4; n++)
          acc[m][n] = __builtin_amdgcn_mfma_f32_16x16x32_f16(af[m], bf[n],
                                                             acc[m][n], 0, 0, 0);
    }
    __syncthreads();
    cur ^= 1;
  }

  // epilogue. C/D frag: row = 4*(lane>>4)+reg, col = lane&15 (verified).
  float bcol[4];
#pragma unroll
  for (int n = 0; n < 4; n++) bcol[n] = bias[bn + wc + n * 16 + r16];

  if (MODE == 1) {
    const int hw = (bn + wc) >> 6;
    const float tsc =
        (bz == 0) ? 1.4426950408889634f / fmaxf(tau[hw], 0.01f) : 1.0f;
    if (bz == 2) {
      // V^T: rows=d (unpermuted), cols=s permuted within each 64-tile
#pragma unroll
      for (int m = 0; m < 4; m++)
#pragma unroll
        for (int r = 0; r < 4; r++) {
          const int rr = bm + wr + m * 16 + g * 4 + r;
          const int s = rr >> 1, bb = rr & 1;
          const int si = s & 63;
          const int sp = (s & ~63) | ((si & 12) << 2) | ((si & 32) >> 2) |
                         ((si & 16) >> 2) | (si & 3);
#pragma unroll
          for (int n = 0; n < 4; n++) {
            const float v = acc[m][n][r] + bcol[n];
            vtdst[((size_t)(bb * NH + hw) * HDIM + n * 16 + r16) * S_LEN + sp] =
                (_Float16)v;
          }
        }
    } else {
      // q/k: d permuted. d = 16n + r16 -> pos = pbase + 4n
      const int pbase = ((r16 >> 2) << 4) | (r16 & 3);
      _Float16* dst = (_Float16*)dstv + (size_t)bz * MROWS * EMB;
#pragma unroll
      for (int m = 0; m < 4; m++)
#pragma unroll
        for (int r = 0; r < 4; r++) {
          float v[4], ss = 0.f;
#pragma unroll
          for (int n = 0; n < 4; n++) {
            v[n] = acc[m][n][r] + bcol[n];
            ss += v[n] * v[n];
          }
          ss += __shfl_xor(ss, 1, 64);
          ss += __shfl_xor(ss, 2, 64);
          ss += __shfl_xor(ss, 4, 64);
          ss += __shfl_xor(ss, 8, 64);
          const float sc = tsc / fmaxf(sqrtf(ss), 1e-12f);
          const int rr = bm + wr + m * 16 + g * 4 + r;
          const int s = rr >> 1, bb = rr & 1;
          const size_t rowb = (((size_t)(bb * NH + hw)) * S_LEN + s) * HDIM;
#pragma unroll
          for (int n = 0; n < 4; n++)
            dst[rowb + pbase + 4 * n] = (_Float16)(v[n] * sc);
        }
    }
  } else {
#pragma unroll
    for (int m = 0; m < 4; m++) {
      const int grow = bm + wr + m * 16 + g * 4;
#pragma unroll
      for (int n = 0; n < 4; n++) {
        const int gcol = bn + wc + n * 16 + r16;
#pragma unroll
        for (int r = 0; r < 4; r++)
          ((float*)dstv)[(size_t)(grow + r) * EMB + gcol] =
              acc[m][n][r] + bcol[n];
      }
    }
  }
}

// ---------------------------------------------------------------------------
// Flash attention, swapped-QK^T, T15 two-tile software pipeline with 4 LDS
// buffers: per slot, QK^T(t+1) MFMA overlaps softmax(t) VALU; V-frag ds_reads
// issue before softmax (latency hidden). All operand frags are single
// ds_read_b128 (perm'd q/k/V^T layouts). exp2-domain softmax, T13 defer-
// rescale THR=8, lazy cross-lane l, packed P-convert. 4 waves x 32 q-rows.
// ---------------------------------------------------------------------------
__global__ __launch_bounds__(256, 1) void attn_fwd(
    const _Float16* __restrict__ qn, const _Float16* __restrict__ kn,
    const _Float16* __restrict__ vt, _Float16* __restrict__ outp) {
  __shared__ __align__(16) _Float16 Kt[4][64 * 64];  // [key][d-perm], swizzled
  __shared__ __align__(16) _Float16 Vt[4][64 * 64];  // [d][key-perm], swizzled

  const int tid = threadIdx.x, lane = tid & 63, w = tid >> 6;
  const int g = lane >> 4, r16 = lane & 15;
  const int s7 = (r16 & 7) << 4;

  // XCD swizzle: nwg = 512, 16 q-tiles (x) fastest
  int flat = blockIdx.x + (blockIdx.y << 4);
  flat = (flat & 7) * 64 + (flat >> 3);
  const int bx = flat & 15, bh = flat >> 4;
  const int b = bh >> 4, h = bh & 15;
  const int q0 = bx * 128;

  const _Float16* Q = qn + (size_t)bh * S_LEN * HDIM;
  const _Float16* Kp = kn + (size_t)bh * S_LEN * HDIM;
  const _Float16* VTp = vt + (size_t)bh * HDIM * S_LEN;

  // Q frags (perm'd d): single b128 per (qg, kk)
  half8v qf[2][2];
#pragma unroll
  for (int qg = 0; qg < 2; qg++) {
    const _Float16* qp = Q + (size_t)(q0 + w * 32 + qg * 16 + r16) * HDIM;
#pragma unroll
    for (int kk = 0; kk < 2; kk++)
      qf[qg][kk] = *(const half8v*)(qp + g * 16 + kk * 8);
  }

  f32x4 o[2][4];
#pragma unroll
  for (int qg = 0; qg < 2; qg++)
#pragma unroll
    for (int n = 0; n < 4; n++) o[qg][n] = (f32x4){0.f, 0.f, 0.f, 0.f};
  float mr[2] = {-1e30f, -1e30f};
  float lr[2] = {0.f, 0.f};

  auto stage2 = [&](int bi, int t0) {
#pragma unroll
    for (int i = 0; i < 2; i++) {
      const int base = (w << 11) + (i << 10);
      const int doff = base + (lane << 4);
      const int row = doff >> 7;
      const int colh = ((doff & 127) ^ ((row & 7) << 4)) >> 1;
      gl_lds16(Kp + (size_t)(t0 + row) * HDIM + colh, (char*)(Kt[bi]) + base);
      gl_lds16(VTp + (size_t)row * S_LEN + t0 + colh, (char*)(Vt[bi]) + base);
    }
  };

  auto qkt = [&](const _Float16* ktile, f32x4 (&sv)[2][4]) {
#pragma unroll
    for (int qg = 0; qg < 2; qg++)
#pragma unroll
      for (int n = 0; n < 4; n++) sv[qg][n] = (f32x4){0.f, 0.f, 0.f, 0.f};
    __builtin_amdgcn_s_setprio(1);
#pragma unroll
    for (int n = 0; n < 4; n++) {
      const char* kb = (const char*)ktile + ((n * 16 + r16) << 7);
      const half8v kf0 = *(const half8v*)(kb + ((g << 5) ^ s7));
      const half8v kf1 = *(const half8v*)(kb + (((g << 5) + 16) ^ s7));
#pragma unroll
      for (int qg = 0; qg < 2; qg++) {
        sv[qg][n] = __builtin_amdgcn_mfma_f32_16x16x32_f16(kf0, qf[qg][0],
                                                           sv[qg][n], 0, 0, 0);
        sv[qg][n] = __builtin_amdgcn_mfma_f32_16x16x32_f16(kf1, qf[qg][1],
                                                           sv[qg][n], 0, 0, 0);
      }
    }
    __builtin_amdgcn_s_setprio(0);
  };

  auto vload = [&](const _Float16* vtile, half8v (&vfr)[4][2]) {
#pragma unroll
    for (int n = 0; n < 4; n++) {
      const char* vb = (const char*)vtile + ((n * 16 + r16) << 7);
      vfr[n][0] = *(const half8v*)(vb + ((g << 5) ^ s7));
      vfr[n][1] = *(const half8v*)(vb + (((g << 5) + 16) ^ s7));
    }
  };

  auto softmax = [&](int qgsel, f32x4 (&sv)[2][4], half8v (&pf)[2][2]) {
    (void)qgsel;
#pragma unroll
    for (int qg = 0; qg < 2; qg++) {
      float pm = -1e30f;
#pragma unroll
      for (int n = 0; n < 4; n++)
#pragma unroll
        for (int r = 0; r < 4; r++) pm = fmaxf(pm, sv[qg][n][r]);
      pm = fmaxf(pm, __shfl_xor(pm, 16, 64));
      pm = fmaxf(pm, __shfl_xor(pm, 32, 64));
      float mn;
      if (__all(pm - mr[qg] <= 8.0f)) {
        mn = mr[qg];  // deferred: p <= 2^8, f16-safe
      } else {
        mn = fmaxf(mr[qg], pm);
        const float scq = __builtin_amdgcn_exp2f(mr[qg] - mn);
        mr[qg] = mn;
        lr[qg] *= scq;
        float srow[4];
#pragma unroll
        for (int r = 0; r < 4; r++) srow[r] = __shfl(scq, 4 * g + r, 64);
#pragma unroll
        for (int n = 0; n < 4; n++)
#pragma unroll
          for (int r = 0; r < 4; r++) o[qg][n][r] *= srow[r];
      }
      float ps = 0.f;
#pragma unroll
      for (int n = 0; n < 4; n++)
#pragma unroll
        for (int r = 0; r < 4; r++) {
          const float p = __builtin_amdgcn_exp2f(sv[qg][n][r] - mn);
          sv[qg][n][r] = p;
          ps += p;
        }
      lr[qg] += ps;
#pragma unroll
      for (int kk = 0; kk < 2; kk++) {
        union { half8v v8; half2v v2[4]; } u;
        u.v2[0] = pk2(sv[qg][2 * kk][0], sv[qg][2 * kk][1]);
        u.v2[1] = pk2(sv[qg][2 * kk][2], sv[qg][2 * kk][3]);
        u.v2[2] = pk2(sv[qg][2 * kk + 1][0], sv[qg][2 * kk + 1][1]);
        u.v2[3] = pk2(sv[qg][2 * kk + 1][2], sv[qg][2 * kk + 1][3]);
        pf[qg][kk] = u.v8;
      }
    }
  };

  auto pvmm = [&](half8v (&pf)[2][2], half8v (&vfr)[4][2]) {
    __builtin_amdgcn_s_setprio(1);
#pragma unroll
    for (int n = 0; n < 4; n++)
#pragma unroll
      for (int qg = 0; qg < 2; qg++) {
        o[qg][n] = __builtin_amdgcn_mfma_f32_16x16x32_f16(pf[qg][0], vfr[n][0],
                                                          o[qg][n], 0, 0, 0);
        o[qg][n] = __builtin_amdgcn_mfma_f32_16x16x32_f16(pf[qg][1], vfr[n][1],
                                                          o[qg][n], 0, 0, 0);
      }
    __builtin_amdgcn_s_setprio(0);
  };

  // prologue: tiles 0,1 into buffers 0,1
  stage2(0, 0);
  stage2(1, 64);
  __syncthreads();

  f32x4 svA[2][4], svB[2][4];
  half8v pfA[2][2], pfB[2][2], vfr[4][2];
  qkt(Kt[0], svA);

  for (int it = 0; it < 16; it++) {
    const int t = it * 2;
    // ---- slot A: consume tile t (svA); produce svB = S(t+1)
    if (t + 2 < 32) stage2((t + 2) & 3, (t + 2) * 64);
    qkt(Kt[(t + 1) & 3], svB);      // MFMA pipe (indep of softmax below)
    vload(Vt[t & 3], vfr);          // ds_reads hide under softmax
    softmax(0, svA, pfA);           // VALU pipe
    pvmm(pfA, vfr);
    __syncthreads();
    // ---- slot B: consume tile t+1 (svB); produce svA = S(t+2)
    if (t + 3 < 32) stage2((t + 3) & 3, (t + 3) * 64);
    if (t + 2 < 32) qkt(Kt[(t + 2) & 3], svA);
    vload(Vt[(t + 1) & 3], vfr);
    softmax(0, svB, pfB);
    pvmm(pfB, vfr);
    __syncthreads();
  }

  // epilogue: finish l reduction, out rows q = 4g+r, cols d = 16n+r16
#pragma unroll
  for (int qg = 0; qg < 2; qg++) {
    float lf = lr[qg];
    lf += __shfl_xor(lf, 16, 64);
    lf += __shfl_xor(lf, 32, 64);
    const float li = 1.0f / lf;
    float lrow[4];
#pragma unroll
    for (int r = 0; r < 4; r++) lrow[r] = __shfl(li, 4 * g + r, 64);
#pragma unroll
    for (int n = 0; n < 4; n++) {
      const int e = h * HDIM + n * 16 + r16;
#pragma unroll
      for (int r = 0; r < 4; r++) {
        const int srow = q0 + w * 32 + qg * 16 + 4 * g + r;
        outp[((size_t)srow * BATCH + b) * EMB + e] =
            (_Float16)(o[qg][n][r] * lrow[r]);
      }
    }
  }
}

// ---------------------------------------------------------------------------
extern "C" void kernel_launch(void* const* d_in, const int* in_sizes, int n_in,
                              void* d_out, int out_size, void* d_ws,
                              size_t ws_size, hipStream_t stream) {
  const float* query = (const float*)d_in[0];
  const float* key   = (const float*)d_in[1];
  const float* value = (const float*)d_in[2];
  const float* ipw   = (const float*)d_in[3];  // (3E, E)
  const float* ipb   = (const float*)d_in[4];  // (3E,)
  const float* opw   = (const float*)d_in[5];  // (E, E)
  const float* opb   = (const float*)d_in[6];  // (E,)
  const float* tau   = (const float*)d_in[7];  // (1,H,1,1)

  // workspace (f16): qin|kin|vin, ipw16, opw16, qbuf|kbuf, vbufT; abuf = qin
  _Float16* qin   = (_Float16*)d_ws;
  _Float16* kin   = qin + (size_t)MROWS * EMB;
  _Float16* vin   = kin + (size_t)MROWS * EMB;
  _Float16* ipw16 = vin + (size_t)MROWS * EMB;
  _Float16* opw16 = ipw16 + (size_t)3 * EMB * EMB;
  _Float16* qbuf  = opw16 + (size_t)EMB * EMB;
  _Float16* kbuf  = qbuf + (size_t)MROWS * EMB;
  _Float16* vbufT = kbuf + (size_t)MROWS * EMB;   // (B,H,HD,S)
  _Float16* abuf  = qin;  // qin dead after in-proj

  cvt_all<<<16384, 256, 0, stream>>>(query, key, value, ipw, opw, qin, kin,
                                     vin, ipw16, opw16);

  // fused q/k/v in-projection + per-head L2 norm + tau/log2e fold + perms
  gemm16<1><<<dim3(8, 32, 3), 256, 0, stream>>>(qin, ipw16, ipb, tau, qbuf,
                                                vbufT);

  attn_fwd<<<dim3(16, 32), 256, 0, stream>>>(qbuf, kbuf, vbufT, abuf);

  gemm16<0><<<dim3(8, 32, 1), 256, 0, stream>>>(abuf, opw16, opb, nullptr,
                                                d_out, nullptr);
}

// Round 8
// 249.810 us; speedup vs baseline: 1.3187x; 1.0445x over previous
//
#include <hip/hip_runtime.h>
#include <hip/hip_bf16.h>

// Problem constants (S, B, E, H) = (2048, 2, 1024, 16), HD = 64
#define S_LEN 2048
#define BATCH 2
#define EMB   1024
#define NH    16
#define HDIM  64
#define MROWS (S_LEN * BATCH)   // 4096 rows of the (S,B,E) matrices

typedef _Float16 half2v __attribute__((ext_vector_type(2)));
typedef _Float16 half4v __attribute__((ext_vector_type(4)));
typedef _Float16 half8v __attribute__((ext_vector_type(8)));
typedef float    f32x4  __attribute__((ext_vector_type(4)));

static __device__ __forceinline__ half8v join44(half4v lo, half4v hi) {
  half8v r;
  r[0] = lo[0]; r[1] = lo[1]; r[2] = lo[2]; r[3] = lo[3];
  r[4] = hi[0]; r[5] = hi[1]; r[6] = hi[2]; r[7] = hi[3];
  return r;
}

// packed f32x2 -> f16x2 (v_cvt_pkrtz_f16_f32)
static __device__ __forceinline__ half2v pk2(float a, float b) {
  auto t = __builtin_amdgcn_cvt_pkrtz(a, b);
  half2v r;
  __builtin_memcpy(&r, &t, sizeof(r));
  return r;
}

// async global->LDS, 16B per lane. dst = wave-uniform base (HW adds lane*16).
static __device__ __forceinline__ void gl_lds16(const _Float16* src, void* dst) {
  __builtin_amdgcn_global_load_lds(
      (const __attribute__((address_space(1))) void*)src,
      (__attribute__((address_space(3))) void*)dst, 16, 0, 0);
}

// ---------------------------------------------------------------------------
// Fused f32 -> f16 convert of all five arrays (q, k, v, ipw, opw).
// ---------------------------------------------------------------------------
__global__ __launch_bounds__(256) void cvt_all(
    const float* __restrict__ q, const float* __restrict__ k,
    const float* __restrict__ v, const float* __restrict__ ipw,
    const float* __restrict__ opw, _Float16* __restrict__ qo,
    _Float16* __restrict__ ko, _Float16* __restrict__ vo,
    _Float16* __restrict__ ipo, _Float16* __restrict__ opo) {
  const int i = blockIdx.x * 256 + threadIdx.x;
  const float* src;
  _Float16* dst;
  int off;
  if (i < 1048576) { src = q; dst = qo; off = i; }
  else if (i < 2097152) { src = k; dst = ko; off = i - 1048576; }
  else if (i < 3145728) { src = v; dst = vo; off = i - 2097152; }
  else if (i < 3932160) { src = ipw; dst = ipo; off = i - 3145728; }
  else { src = opw; dst = opo; off = i - 3932160; }
  const float4 f = ((const float4*)src)[off];
  half4v hv;
  hv[0] = (_Float16)f.x; hv[1] = (_Float16)f.y;
  hv[2] = (_Float16)f.z; hv[3] = (_Float16)f.w;
  ((half4v*)dst)[off] = hv;
}

// ---------------------------------------------------------------------------
// Stage one 128x64-half tile (16KB) via 4 gload_lds per wave, T2 XOR swizzle
// applied to the GLOBAL source granule (rule 21: linear LDS dest).
// ---------------------------------------------------------------------------
static __device__ __forceinline__ void stage_tile(const _Float16* gsrc,
                                                  _Float16* lds, int w,
                                                  int lane) {
#pragma unroll
  for (int i = 0; i < 4; i++) {
    const int base = (w << 12) + (i << 10);
    const int doff = base + (lane << 4);
    const int row = doff >> 7;
    const int colb = (doff & 127) ^ ((row & 7) << 4);
    gl_lds16(gsrc + (size_t)row * EMB + (colb >> 1), (char*)lds + base);
  }
}

// Stage one 64x64-half tile (8KB) via 2 gload_lds per wave (same swizzle).
static __device__ __forceinline__ void stage_tile_b(const _Float16* gsrc,
                                                    _Float16* lds, int w,
                                                    int lane) {
#pragma unroll
  for (int i = 0; i < 2; i++) {
    const int base = (w << 11) + (i << 10);
    const int doff = base + (lane << 4);
    const int row = doff >> 7;
    const int colb = (doff & 127) ^ ((row & 7) << 4);
    gl_lds16(gsrc + (size_t)row * EMB + (colb >> 1), (char*)lds + base);
  }
}

// ---------------------------------------------------------------------------
// TN GEMM: C[M,N] = A[M,K] @ W[N,K]^T + bias[N]. All-f16 operands, K=1024,
// tile 128x64, BK=64, double-buffered, 48KB LDS -> 3 blocks/CU, XCD-swizzled.
// Wave w owns rows w*32..w*32+31 x all 64 cols (acc[2][4]) so the in-proj
// epilogue norm sees a full 64-wide head per wave.
// MODE 1 (in-proj): z selects q/k/v.
//   z=0: L2-normalize + fold log2e/clip(tau,.01); (B,H,S,HD) f16, d PERMUTED.
//   z=1: L2-normalize; (B,H,S,HD) f16, d PERMUTED.
//   z=2: raw; V TRANSPOSED per head [bh][d][s], s PERMUTED within 64-tiles.
//   perm(k): pos = ((k&12)<<2) | ((k&32)>>2) | ((k&16)>>2) | (k&3)
// MODE 0 (out-proj): f32 row-major out.
// ---------------------------------------------------------------------------
template <int MODE>
__global__ __launch_bounds__(256, 3) void gemm16(
    const _Float16* __restrict__ Abase, const _Float16* __restrict__ Wbase,
    const float* __restrict__ ball, const float* __restrict__ tau,
    void* __restrict__ dstv, _Float16* __restrict__ vtdst) {
  __shared__ __align__(16) _Float16 As[2][128 * 64];
  __shared__ __align__(16) _Float16 Bs[2][64 * 64];

  const int tid = threadIdx.x, lane = tid & 63, w = tid >> 6;
  const int g = lane >> 4, r16 = lane & 15;

  // XCD-aware bijective swizzle of the flat block id (bx fastest)
  constexpr int NWG = MODE ? 1536 : 512;
  constexpr int CHUNK = NWG / 8;
  int flat = blockIdx.x + 16 * (blockIdx.y + 32 * blockIdx.z);
  flat = (flat & 7) * CHUNK + (flat >> 3);
  const int bx = flat & 15;
  const int by = (flat >> 4) & 31;
  const int bz = MODE ? (flat >> 9) : 0;

  const int bm = by * 128, bn = bx * 64;
  const int wr = w * 32;  // wave's row offset in tile
  const int swz = (r16 & 7) << 4;

  const _Float16* A = Abase + (MODE ? (size_t)bz * MROWS * EMB : 0);
  const _Float16* W = Wbase + (MODE ? (size_t)bz * EMB * EMB : 0);
  const float* bias = ball + (MODE ? bz * EMB : 0);

  f32x4 acc[2][4];
#pragma unroll
  for (int m = 0; m < 2; m++)
#pragma unroll
    for (int n = 0; n < 4; n++) acc[m][n] = (f32x4){0.f, 0.f, 0.f, 0.f};

  const _Float16* Ap = A + (size_t)bm * EMB;
  const _Float16* Wp = W + (size_t)bn * EMB;

  stage_tile(Ap, As[0], w, lane);
  stage_tile_b(Wp, Bs[0], w, lane);
  __syncthreads();

  int cur = 0;
  for (int t = 0; t < 16; t++) {
    if (t < 15) {
      stage_tile(Ap + (t + 1) * 64, As[cur ^ 1], w, lane);
      stage_tile_b(Wp + (t + 1) * 64, Bs[cur ^ 1], w, lane);
    }
#pragma unroll
    for (int kk = 0; kk < 2; kk++) {
      half8v af[2], bf[4];
      const int cA = kk * 64 + (g << 3);
#pragma unroll
      for (int m = 0; m < 2; m++) {
        const char* rb = (const char*)(As[cur]) + ((wr + m * 16 + r16) << 7);
        af[m] = join44(*(const half4v*)(rb + (cA ^ swz)),
                       *(const half4v*)(rb + ((cA + 32) ^ swz)));
      }
#pragma unroll
      for (int n = 0; n < 4; n++) {
        const char* rb = (const char*)(Bs[cur]) + ((n * 16 + r16) << 7);
        bf[n] = join44(*(const half4v*)(rb + (cA ^ swz)),
                       *(const half4v*)(rb + ((cA + 32) ^ swz)));
      }
#pragma unroll
      for (int m = 0; m < 2; m++)
#pragma unroll
        for (int n = 0; n < 4; n++)
          acc[m][n] = __builtin_amdgcn_mfma_f32_16x16x32_f16(af[m], bf[n],
                                                             acc[m][n], 0, 0, 0);
    }
    __syncthreads();
    cur ^= 1;
  }

  // epilogue. C/D frag: row = 4*(lane>>4)+reg, col = lane&15 (verified).
  float bcol[4];
#pragma unroll
  for (int n = 0; n < 4; n++) bcol[n] = bias[bn + n * 16 + r16];

  if (MODE == 1) {
    const int hw = bx;  // bn>>6: this block's head
    const float tsc =
        (bz == 0) ? 1.4426950408889634f / fmaxf(tau[hw], 0.01f) : 1.0f;
    if (bz == 2) {
      // V^T: rows=d (unpermuted), cols=s permuted within each 64-tile
#pragma unroll
      for (int m = 0; m < 2; m++)
#pragma unroll
        for (int r = 0; r < 4; r++) {
          const int rr = bm + wr + m * 16 + g * 4 + r;
          const int s = rr >> 1, bb = rr & 1;
          const int si = s & 63;
          const int sp = (s & ~63) | ((si & 12) << 2) | ((si & 32) >> 2) |
                         ((si & 16) >> 2) | (si & 3);
#pragma unroll
          for (int n = 0; n < 4; n++) {
            const float v = acc[m][n][r] + bcol[n];
            vtdst[((size_t)(bb * NH + hw) * HDIM + n * 16 + r16) * S_LEN + sp] =
                (_Float16)v;
          }
        }
    } else {
      // q/k: d permuted. d = 16n + r16 -> pos = pbase + 4n
      const int pbase = ((r16 >> 2) << 4) | (r16 & 3);
      _Float16* dst = (_Float16*)dstv + (size_t)bz * MROWS * EMB;
#pragma unroll
      for (int m = 0; m < 2; m++)
#pragma unroll
        for (int r = 0; r < 4; r++) {
          float v[4], ss = 0.f;
#pragma unroll
          for (int n = 0; n < 4; n++) {
            v[n] = acc[m][n][r] + bcol[n];
            ss += v[n] * v[n];
          }
          ss += __shfl_xor(ss, 1, 64);
          ss += __shfl_xor(ss, 2, 64);
          ss += __shfl_xor(ss, 4, 64);
          ss += __shfl_xor(ss, 8, 64);
          const float sc = tsc / fmaxf(sqrtf(ss), 1e-12f);
          const int rr = bm + wr + m * 16 + g * 4 + r;
          const int s = rr >> 1, bb = rr & 1;
          const size_t rowb = (((size_t)(bb * NH + hw)) * S_LEN + s) * HDIM;
#pragma unroll
          for (int n = 0; n < 4; n++)
            dst[rowb + pbase + 4 * n] = (_Float16)(v[n] * sc);
        }
    }
  } else {
#pragma unroll
    for (int m = 0; m < 2; m++) {
      const int grow = bm + wr + m * 16 + g * 4;
#pragma unroll
      for (int n = 0; n < 4; n++) {
        const int gcol = bn + n * 16 + r16;
#pragma unroll
        for (int r = 0; r < 4; r++)
          ((float*)dstv)[(size_t)(grow + r) * EMB + gcol] =
              acc[m][n][r] + bcol[n];
      }
    }
  }
}

// ---------------------------------------------------------------------------
// Flash attention, swapped-QK^T, T15 two-tile software pipeline with 4 LDS
// buffers: per slot, QK^T(t+1) MFMA overlaps softmax(t) VALU; V-frag ds_reads
// issue before softmax (latency hidden). All operand frags are single
// ds_read_b128 (perm'd q/k/V^T layouts). exp2-domain softmax, T13 defer-
// rescale THR=8, lazy cross-lane l, packed P-convert. 4 waves x 32 q-rows.
// ---------------------------------------------------------------------------
__global__ __launch_bounds__(256, 1) void attn_fwd(
    const _Float16* __restrict__ qn, const _Float16* __restrict__ kn,
    const _Float16* __restrict__ vt, _Float16* __restrict__ outp) {
  __shared__ __align__(16) _Float16 Kt[4][64 * 64];  // [key][d-perm], swizzled
  __shared__ __align__(16) _Float16 Vt[4][64 * 64];  // [d][key-perm], swizzled

  const int tid = threadIdx.x, lane = tid & 63, w = tid >> 6;
  const int g = lane >> 4, r16 = lane & 15;
  const int s7 = (r16 & 7) << 4;

  // XCD swizzle: nwg = 512, 16 q-tiles (x) fastest
  int flat = blockIdx.x + (blockIdx.y << 4);
  flat = (flat & 7) * 64 + (flat >> 3);
  const int bx = flat & 15, bh = flat >> 4;
  const int b = bh >> 4, h = bh & 15;
  const int q0 = bx * 128;

  const _Float16* Q = qn + (size_t)bh * S_LEN * HDIM;
  const _Float16* Kp = kn + (size_t)bh * S_LEN * HDIM;
  const _Float16* VTp = vt + (size_t)bh * HDIM * S_LEN;

  // Q frags (perm'd d): single b128 per (qg, kk)
  half8v qf[2][2];
#pragma unroll
  for (int qg = 0; qg < 2; qg++) {
    const _Float16* qp = Q + (size_t)(q0 + w * 32 + qg * 16 + r16) * HDIM;
#pragma unroll
    for (int kk = 0; kk < 2; kk++)
      qf[qg][kk] = *(const half8v*)(qp + g * 16 + kk * 8);
  }

  f32x4 o[2][4];
#pragma unroll
  for (int qg = 0; qg < 2; qg++)
#pragma unroll
    for (int n = 0; n < 4; n++) o[qg][n] = (f32x4){0.f, 0.f, 0.f, 0.f};
  float mr[2] = {-1e30f, -1e30f};
  float lr[2] = {0.f, 0.f};

  auto stage2 = [&](int bi, int t0) {
#pragma unroll
    for (int i = 0; i < 2; i++) {
      const int base = (w << 11) + (i << 10);
      const int doff = base + (lane << 4);
      const int row = doff >> 7;
      const int colh = ((doff & 127) ^ ((row & 7) << 4)) >> 1;
      gl_lds16(Kp + (size_t)(t0 + row) * HDIM + colh, (char*)(Kt[bi]) + base);
      gl_lds16(VTp + (size_t)row * S_LEN + t0 + colh, (char*)(Vt[bi]) + base);
    }
  };

  auto qkt = [&](const _Float16* ktile, f32x4 (&sv)[2][4]) {
#pragma unroll
    for (int qg = 0; qg < 2; qg++)
#pragma unroll
      for (int n = 0; n < 4; n++) sv[qg][n] = (f32x4){0.f, 0.f, 0.f, 0.f};
    __builtin_amdgcn_s_setprio(1);
#pragma unroll
    for (int n = 0; n < 4; n++) {
      const char* kb = (const char*)ktile + ((n * 16 + r16) << 7);
      const half8v kf0 = *(const half8v*)(kb + ((g << 5) ^ s7));
      const half8v kf1 = *(const half8v*)(kb + (((g << 5) + 16) ^ s7));
#pragma unroll
      for (int qg = 0; qg < 2; qg++) {
        sv[qg][n] = __builtin_amdgcn_mfma_f32_16x16x32_f16(kf0, qf[qg][0],
                                                           sv[qg][n], 0, 0, 0);
        sv[qg][n] = __builtin_amdgcn_mfma_f32_16x16x32_f16(kf1, qf[qg][1],
                                                           sv[qg][n], 0, 0, 0);
      }
    }
    __builtin_amdgcn_s_setprio(0);
  };

  auto vload = [&](const _Float16* vtile, half8v (&vfr)[4][2]) {
#pragma unroll
    for (int n = 0; n < 4; n++) {
      const char* vb = (const char*)vtile + ((n * 16 + r16) << 7);
      vfr[n][0] = *(const half8v*)(vb + ((g << 5) ^ s7));
      vfr[n][1] = *(const half8v*)(vb + (((g << 5) + 16) ^ s7));
    }
  };

  auto softmax = [&](int qgsel, f32x4 (&sv)[2][4], half8v (&pf)[2][2]) {
    (void)qgsel;
#pragma unroll
    for (int qg = 0; qg < 2; qg++) {
      float pm = -1e30f;
#pragma unroll
      for (int n = 0; n < 4; n++)
#pragma unroll
        for (int r = 0; r < 4; r++) pm = fmaxf(pm, sv[qg][n][r]);
      pm = fmaxf(pm, __shfl_xor(pm, 16, 64));
      pm = fmaxf(pm, __shfl_xor(pm, 32, 64));
      float mn;
      if (__all(pm - mr[qg] <= 8.0f)) {
        mn = mr[qg];  // deferred: p <= 2^8, f16-safe
      } else {
        mn = fmaxf(mr[qg], pm);
        const float scq = __builtin_amdgcn_exp2f(mr[qg] - mn);
        mr[qg] = mn;
        lr[qg] *= scq;
        float srow[4];
#pragma unroll
        for (int r = 0; r < 4; r++) srow[r] = __shfl(scq, 4 * g + r, 64);
#pragma unroll
        for (int n = 0; n < 4; n++)
#pragma unroll
          for (int r = 0; r < 4; r++) o[qg][n][r] *= srow[r];
      }
      float ps = 0.f;
#pragma unroll
      for (int n = 0; n < 4; n++)
#pragma unroll
        for (int r = 0; r < 4; r++) {
          const float p = __builtin_amdgcn_exp2f(sv[qg][n][r] - mn);
          sv[qg][n][r] = p;
          ps += p;
        }
      lr[qg] += ps;
#pragma unroll
      for (int kk = 0; kk < 2; kk++) {
        union { half8v v8; half2v v2[4]; } u;
        u.v2[0] = pk2(sv[qg][2 * kk][0], sv[qg][2 * kk][1]);
        u.v2[1] = pk2(sv[qg][2 * kk][2], sv[qg][2 * kk][3]);
        u.v2[2] = pk2(sv[qg][2 * kk + 1][0], sv[qg][2 * kk + 1][1]);
        u.v2[3] = pk2(sv[qg][2 * kk + 1][2], sv[qg][2 * kk + 1][3]);
        pf[qg][kk] = u.v8;
      }
    }
  };

  auto pvmm = [&](half8v (&pf)[2][2], half8v (&vfr)[4][2]) {
    __builtin_amdgcn_s_setprio(1);
#pragma unroll
    for (int n = 0; n < 4; n++)
#pragma unroll
      for (int qg = 0; qg < 2; qg++) {
        o[qg][n] = __builtin_amdgcn_mfma_f32_16x16x32_f16(pf[qg][0], vfr[n][0],
                                                          o[qg][n], 0, 0, 0);
        o[qg][n] = __builtin_amdgcn_mfma_f32_16x16x32_f16(pf[qg][1], vfr[n][1],
                                                          o[qg][n], 0, 0, 0);
      }
    __builtin_amdgcn_s_setprio(0);
  };

  // prologue: tiles 0,1 into buffers 0,1
  stage2(0, 0);
  stage2(1, 64);
  __syncthreads();

  f32x4 svA[2][4], svB[2][4];
  half8v pfA[2][2], pfB[2][2], vfr[4][2];
  qkt(Kt[0], svA);

  for (int it = 0; it < 16; it++) {
    const int t = it * 2;
    // ---- slot A: consume tile t (svA); produce svB = S(t+1)
    if (t + 2 < 32) stage2((t + 2) & 3, (t + 2) * 64);
    qkt(Kt[(t + 1) & 3], svB);      // MFMA pipe (indep of softmax below)
    vload(Vt[t & 3], vfr);          // ds_reads hide under softmax
    softmax(0, svA, pfA);           // VALU pipe
    pvmm(pfA, vfr);
    __syncthreads();
    // ---- slot B: consume tile t+1 (svB); produce svA = S(t+2)
    if (t + 3 < 32) stage2((t + 3) & 3, (t + 3) * 64);
    if (t + 2 < 32) qkt(Kt[(t + 2) & 3], svA);
    vload(Vt[(t + 1) & 3], vfr);
    softmax(0, svB, pfB);
    pvmm(pfB, vfr);
    __syncthreads();
  }

  // epilogue: finish l reduction, out rows q = 4g+r, cols d = 16n+r16
#pragma unroll
  for (int qg = 0; qg < 2; qg++) {
    float lf = lr[qg];
    lf += __shfl_xor(lf, 16, 64);
    lf += __shfl_xor(lf, 32, 64);
    const float li = 1.0f / lf;
    float lrow[4];
#pragma unroll
    for (int r = 0; r < 4; r++) lrow[r] = __shfl(li, 4 * g + r, 64);
#pragma unroll
    for (int n = 0; n < 4; n++) {
      const int e = h * HDIM + n * 16 + r16;
#pragma unroll
      for (int r = 0; r < 4; r++) {
        const int srow = q0 + w * 32 + qg * 16 + 4 * g + r;
        outp[((size_t)srow * BATCH + b) * EMB + e] =
            (_Float16)(o[qg][n][r] * lrow[r]);
      }
    }
  }
}

// ---------------------------------------------------------------------------
extern "C" void kernel_launch(void* const* d_in, const int* in_sizes, int n_in,
                              void* d_out, int out_size, void* d_ws,
                              size_t ws_size, hipStream_t stream) {
  const float* query = (const float*)d_in[0];
  const float* key   = (const float*)d_in[1];
  const float* value = (const float*)d_in[2];
  const float* ipw   = (const float*)d_in[3];  // (3E, E)
  const float* ipb   = (const float*)d_in[4];  // (3E,)
  const float* opw   = (const float*)d_in[5];  // (E, E)
  const float* opb   = (const float*)d_in[6];  // (E,)
  const float* tau   = (const float*)d_in[7];  // (1,H,1,1)

  // workspace (f16): qin|kin|vin, ipw16, opw16, qbuf|kbuf, vbufT; abuf = qin
  _Float16* qin   = (_Float16*)d_ws;
  _Float16* kin   = qin + (size_t)MROWS * EMB;
  _Float16* vin   = kin + (size_t)MROWS * EMB;
  _Float16* ipw16 = vin + (size_t)MROWS * EMB;
  _Float16* opw16 = ipw16 + (size_t)3 * EMB * EMB;
  _Float16* qbuf  = opw16 + (size_t)EMB * EMB;
  _Float16* kbuf  = qbuf + (size_t)MROWS * EMB;
  _Float16* vbufT = kbuf + (size_t)MROWS * EMB;   // (B,H,HD,S)
  _Float16* abuf  = qin;  // qin dead after in-proj

  cvt_all<<<16384, 256, 0, stream>>>(query, key, value, ipw, opw, qin, kin,
                                     vin, ipw16, opw16);

  // fused q/k/v in-projection + per-head L2 norm + tau/log2e fold + perms
  gemm16<1><<<dim3(16, 32, 3), 256, 0, stream>>>(qin, ipw16, ipb, tau, qbuf,
                                                 vbufT);

  attn_fwd<<<dim3(16, 32), 256, 0, stream>>>(qbuf, kbuf, vbufT, abuf);

  gemm16<0><<<dim3(16, 32, 1), 256, 0, stream>>>(abuf, opw16, opb, nullptr,
                                                 d_out, nullptr);
}